// Round 1
// baseline (621.068 us; speedup 1.0000x reference)
//
#include <hip/hip_runtime.h>
#include <hip/hip_bf16.h>

typedef float v4f __attribute__((ext_vector_type(4)));
typedef short short8 __attribute__((ext_vector_type(8)));

__device__ inline ushort f2bf(float x) {
    unsigned u = __float_as_uint(x);
    unsigned r = u + 0x7fffu + ((u >> 16) & 1u);
    return (ushort)(r >> 16);
}

// ---------------- K_prep: blocks 0..191 = t_attn GEMM tile; blocks 192..255 = wd_sum + WdaT bf16 cvt ----------------
__global__ __launch_bounds__(256) void k_prep(const float* __restrict__ text,
                                              const float* __restrict__ pos,
                                              const float* __restrict__ Wt,
                                              const float* __restrict__ Wpa,
                                              const float* __restrict__ b_attn,
                                              const float* __restrict__ Wda,
                                              float* __restrict__ t_attn,
                                              float* __restrict__ wd_sum,
                                              ushort* __restrict__ wdat) {
    __shared__ float At[64][68];
    __shared__ float Bt[64][64];
    int t = threadIdx.x;
    int bid = blockIdx.x;
    if (bid >= 192) {
        // wd_sum[k] = sum_o Wda[k][o]; wdat[o][k] = bf16(Wda[k][o])
        int k = bid - 192;
        float a0 = Wda[(size_t)k * 768 + t];
        float a1 = Wda[(size_t)k * 768 + 256 + t];
        float a2 = Wda[(size_t)k * 768 + 512 + t];
        wdat[(size_t)t * 64 + k]         = f2bf(a0);
        wdat[(size_t)(t + 256) * 64 + k] = f2bf(a1);
        wdat[(size_t)(t + 512) * 64 + k] = f2bf(a2);
        float s = a0 + a1 + a2;
#pragma unroll
        for (int off = 32; off; off >>= 1) s += __shfl_down(s, off, 64);
        if ((t & 63) == 0) At[0][t >> 6] = s;
        __syncthreads();
        if (t == 0) wd_sum[k] = At[0][0] + At[0][1] + At[0][2] + At[0][3];
        return;
    }
    int M0 = (bid & 15) * 64, N0 = (bid >> 4) * 64;
    int r0 = (t >> 4) * 4, o0 = (t & 15) * 4;
    float acc[16] = {};
    for (int kc = 0; kc < 13; ++kc) {
        __syncthreads();
        for (int f = t * 4; f < 4096; f += 1024) {
            int row = f >> 6, kcol = f & 63;
            float4 v;
            if (kc < 12) v = *(const float4*)&text[(size_t)(M0 + row) * 768 + kc * 64 + kcol];
            else         v = *(const float4*)&pos[(size_t)(M0 + row) * 64 + kcol];
            At[kcol + 0][row] = v.x; At[kcol + 1][row] = v.y;
            At[kcol + 2][row] = v.z; At[kcol + 3][row] = v.w;
        }
        for (int f = t * 4; f < 4096; f += 1024) {
            int kr = f >> 6, oc = f & 63;
            float4 v;
            if (kc < 12) v = *(const float4*)&Wt[(size_t)(kc * 64 + kr) * 768 + N0 + oc];
            else         v = *(const float4*)&Wpa[(size_t)kr * 768 + N0 + oc];
            *(float4*)&Bt[kr][oc] = v;
        }
        __syncthreads();
#pragma unroll 8
        for (int k = 0; k < 64; ++k) {
            float4 a = *(const float4*)&At[k][r0];
            float4 b = *(const float4*)&Bt[k][o0];
            float av[4] = {a.x, a.y, a.z, a.w};
            float bv[4] = {b.x, b.y, b.z, b.w};
#pragma unroll
            for (int i = 0; i < 4; ++i)
#pragma unroll
                for (int j = 0; j < 4; ++j) acc[i * 4 + j] += av[i] * bv[j];
        }
    }
    float4 bias = *(const float4*)&b_attn[N0 + o0];
    float bb[4] = {bias.x, bias.y, bias.z, bias.w};
#pragma unroll
    for (int i = 0; i < 4; ++i) {
        float4 o;
        o.x = acc[i * 4 + 0] + bb[0]; o.y = acc[i * 4 + 1] + bb[1];
        o.z = acc[i * 4 + 2] + bb[2]; o.w = acc[i * 4 + 3] + bb[3];
        *(float4*)&t_attn[(size_t)(M0 + r0 + i) * 768 + N0 + o0] = o;
    }
}

// ---------------- K2 (mega): scores -> softmax -> p, pd (fp32), r GEMM (bf16 MFMA, swapped operands) ----------------
__global__ __launch_bounds__(256) void k_mega(const float* __restrict__ dep,
                                              const int* __restrict__ adj,
                                              const ushort* __restrict__ wdat,
                                              const float* __restrict__ t_attn,
                                              const float* __restrict__ wd_sum,
                                              float* __restrict__ r_out,
                                              float* __restrict__ out_p,
                                              float* __restrict__ pd_out) {
    __shared__ __align__(16) ushort db[128 * 72];  // dep tile bf16, [j][64k + 8 pad]
    __shared__ float wds[64];
    __shared__ float sc[128];
    __shared__ float pv[128];
    __shared__ float pdp[4][64];
    __shared__ float red[8];
    int t = threadIdx.x;
    int bi = blockIdx.x;
    const float* depb = dep + (size_t)bi * (128 * 64);
    // stage dep -> bf16 LDS (row-major [j][k], +8 pad)
#pragma unroll
    for (int it = 0; it < 8; ++it) {
        int f = t + it * 256;              // float4 index, 0..2047
        int j = f >> 4, k4 = f & 15;
        float4 v = *(const float4*)&depb[(size_t)f * 4];
        union { ushort u[4]; uint2 d; } pk;
        pk.u[0] = f2bf(v.x); pk.u[1] = f2bf(v.y);
        pk.u[2] = f2bf(v.z); pk.u[3] = f2bf(v.w);
        *(uint2*)&db[j * 72 + k4 * 4] = pk.d;
    }
    if (t < 64) wds[t] = wd_sum[t];
    const float* ta = t_attn + (size_t)bi * 768;
    // S_t = sum over o of t_attn row
    float s = ta[t] + ta[t + 256] + ta[t + 512];
#pragma unroll
    for (int off = 32; off; off >>= 1) s += __shfl_down(s, off, 64);
    if ((t & 63) == 0) red[t >> 6] = s;
    __syncthreads();
    float S_t = red[0] + red[1] + red[2] + red[3];
    // scores (fp32, dep from L2-hot global)
    if (t < 128) {
        const float* row = depb + (size_t)t * 64;
        float d = 0.f;
#pragma unroll
        for (int k4 = 0; k4 < 16; ++k4) {
            float4 v = *(const float4*)&row[k4 * 4];
            d += v.x * wds[k4 * 4 + 0] + v.y * wds[k4 * 4 + 1]
               + v.z * wds[k4 * 4 + 2] + v.w * wds[k4 * 4 + 3];
        }
        float sval = S_t + d;
        if (adj[(size_t)bi * 128 + t] == 0) sval += -1e30f;
        sc[t] = sval;
    }
    __syncthreads();
    if (t < 64) {
        float v = fmaxf(sc[t], sc[t + 64]);
#pragma unroll
        for (int off = 32; off; off >>= 1) v = fmaxf(v, __shfl_down(v, off, 64));
        if (t == 0) red[4] = v;
    }
    __syncthreads();
    if (t < 128) pv[t] = __expf(sc[t] - red[4]);
    __syncthreads();
    if (t < 64) {
        float v = pv[t] + pv[t + 64];
#pragma unroll
        for (int off = 32; off; off >>= 1) v += __shfl_down(v, off, 64);
        if (t == 0) red[5] = v;
    }
    __syncthreads();
    float inv = 1.0f / red[5];
    if (t < 128) {
        float pj = pv[t] * inv;
        pv[t] = pj;
        out_p[(size_t)bi * 128 + t] = pj;
    }
    __syncthreads();
    // pd[k] = sum_j p[j] * dep[j][k]  (fp32 from L2-hot global)
    {
        int kk = t & 63, seg = t >> 6;
        float a = 0.f;
#pragma unroll
        for (int jj = 0; jj < 32; ++jj)
            a += pv[seg * 32 + jj] * depb[(size_t)(seg * 32 + jj) * 64 + kk];
        pdp[seg][kk] = a;
    }
    __syncthreads();
    if (t < 64) pd_out[(size_t)bi * 64 + t] = pdp[0][t] + pdp[1][t] + pdp[2][t] + pdp[3][t];

    // ---- r GEMM via bf16 MFMA 16x16x32, SWAPPED operands: D'[o][j] so each lane holds
    // 4 consecutive o of one row j -> float4 nontemporal stores (384 dword -> 96 dwordx4) ----
    int w = t >> 6, l = t & 63;
    int col = l & 15, q = l >> 4;
    short8 afr[2][2];
#pragma unroll
    for (int jt = 0; jt < 2; ++jt)
#pragma unroll
        for (int h = 0; h < 2; ++h)
            afr[jt][h] = *(const short8*)&db[(w * 32 + jt * 16 + col) * 72 + h * 32 + q * 8];
    float* rb = r_out + (size_t)bi * (128 * 768);
    for (int oc = 0; oc < 12; ++oc) {
        int O = oc * 64;
        short8 bfr[4][2];
#pragma unroll
        for (int ot = 0; ot < 4; ++ot)
#pragma unroll
            for (int h = 0; h < 2; ++h)
                bfr[ot][h] = *(const short8*)&wdat[(size_t)(O + ot * 16 + col) * 64 + h * 32 + q * 8];
        float4 tav[4];
#pragma unroll
        for (int ot = 0; ot < 4; ++ot) tav[ot] = *(const float4*)&ta[O + ot * 16 + q * 4];
#pragma unroll
        for (int ot = 0; ot < 4; ++ot) {
#pragma unroll
            for (int jt = 0; jt < 2; ++jt) {
                v4f acc = {0.f, 0.f, 0.f, 0.f};
                // D' = WdaT x dep^T : col = lane&15 = j_local, row = q*4+reg = o_local
                acc = __builtin_amdgcn_mfma_f32_16x16x32_bf16(bfr[ot][0], afr[jt][0], acc, 0, 0, 0);
                acc = __builtin_amdgcn_mfma_f32_16x16x32_bf16(bfr[ot][1], afr[jt][1], acc, 0, 0, 0);
                v4f o4;
                o4[0] = acc[0] + tav[ot].x;
                o4[1] = acc[1] + tav[ot].y;
                o4[2] = acc[2] + tav[ot].z;
                o4[3] = acc[3] + tav[ot].w;
                v4f* dst = (v4f*)(rb + (size_t)(w * 32 + jt * 16 + col) * 768 + O + ot * 16 + q * 4);
                __builtin_nontemporal_store(o4, dst);
            }
        }
    }
}

// ---------------- K3: output_sum = text + pos@Wp + bp + bd + pd@Wd (256 blocks x 4 rows) ----------------
__global__ __launch_bounds__(256) void k_out(const float* __restrict__ text,
                                             const float* __restrict__ pos,
                                             const float* __restrict__ Wp,
                                             const float* __restrict__ bp,
                                             const float* __restrict__ Wd,
                                             const float* __restrict__ bd,
                                             const float* __restrict__ pd,
                                             float* __restrict__ outp) {
    __shared__ float ps[4][64];
    __shared__ float pdl[4][64];
    int t = threadIdx.x;
    int bi0 = blockIdx.x * 4;
    {
        int g = t >> 6, k = t & 63;
        ps[g][k]  = pos[(size_t)(bi0 + g) * 64 + k];
        pdl[g][k] = pd[(size_t)(bi0 + g) * 64 + k];
    }
    __syncthreads();
    if (t < 192) {
        int d0 = t * 4;
        float acc[16] = {};
#pragma unroll 4
        for (int k = 0; k < 64; ++k) {
            float4 wp = *(const float4*)&Wp[(size_t)k * 768 + d0];
            float4 wd = *(const float4*)&Wd[(size_t)k * 768 + d0];
            float wpv[4] = {wp.x, wp.y, wp.z, wp.w};
            float wdv[4] = {wd.x, wd.y, wd.z, wd.w};
#pragma unroll
            for (int g = 0; g < 4; ++g) {
                float pk = ps[g][k], dk = pdl[g][k];
#pragma unroll
                for (int c = 0; c < 4; ++c) acc[g * 4 + c] += pk * wpv[c] + dk * wdv[c];
            }
        }
        float4 bpv = *(const float4*)&bp[d0];
        float4 bdv = *(const float4*)&bd[d0];
        float bb[4] = {bpv.x + bdv.x, bpv.y + bdv.y, bpv.z + bdv.z, bpv.w + bdv.w};
#pragma unroll
        for (int g = 0; g < 4; ++g) {
            float4 tx = *(const float4*)&text[(size_t)(bi0 + g) * 768 + d0];
            float4 o;
            o.x = acc[g * 4 + 0] + tx.x + bb[0];
            o.y = acc[g * 4 + 1] + tx.y + bb[1];
            o.z = acc[g * 4 + 2] + tx.z + bb[2];
            o.w = acc[g * 4 + 3] + tx.w + bb[3];
            *(float4*)&outp[(size_t)(bi0 + g) * 768 + d0] = o;
        }
    }
}

extern "C" void kernel_launch(void* const* d_in, const int* in_sizes, int n_in,
                              void* d_out, int out_size, void* d_ws, size_t ws_size,
                              hipStream_t stream) {
    const float* text   = (const float*)d_in[0];
    const int*   adj    = (const int*)d_in[1];
    const float* dep    = (const float*)d_in[2];
    const float* pos    = (const float*)d_in[3];
    const float* Wt     = (const float*)d_in[4];
    const float* Wpa    = (const float*)d_in[5];
    const float* Wda    = (const float*)d_in[6];
    const float* b_attn = (const float*)d_in[7];
    const float* Wd     = (const float*)d_in[8];
    const float* bd     = (const float*)d_in[9];
    const float* Wp     = (const float*)d_in[10];
    const float* bp     = (const float*)d_in[11];

    float* out    = (float*)d_out;
    float* r_out  = out;                                   // [8,128,128,768]
    float* os_out = out + (size_t)8 * 128 * 128 * 768;     // [8,128,768]
    float* p_out  = os_out + (size_t)8 * 128 * 768;        // [8,128,128]

    float* ws     = (float*)d_ws;
    float* t_attn = ws;                    // 786432 floats
    float* wd_sum = ws + 786432;           // 64
    float* pd     = ws + 786496;           // 65536
    ushort* wdat  = (ushort*)(ws + 852032);  // 49152 ushorts, 16B-aligned

    k_prep<<<256, 256, 0, stream>>>(text, pos, Wt, Wpa, b_attn, Wda, t_attn, wd_sum, wdat);
    k_mega<<<1024, 256, 0, stream>>>(dep, adj, wdat, t_attn, wd_sum, r_out, p_out, pd);
    k_out<<<256, 256, 0, stream>>>(text, pos, Wp, bp, Wd, bd, pd, os_out);
}

// Round 2
// 592.343 us; speedup vs baseline: 1.0485x; 1.0485x over previous
//
#include <hip/hip_runtime.h>
#include <hip/hip_bf16.h>

typedef float v4f __attribute__((ext_vector_type(4)));
typedef short short8 __attribute__((ext_vector_type(8)));

__device__ inline ushort f2bf(float x) {
    unsigned u = __float_as_uint(x);
    unsigned r = u + 0x7fffu + ((u >> 16) & 1u);
    return (ushort)(r >> 16);
}

// ---------------- K_prep: blocks 0..191 = t_attn GEMM tile; blocks 192..255 = wd_sum + WdaT bf16 cvt ----------------
__global__ __launch_bounds__(256) void k_prep(const float* __restrict__ text,
                                              const float* __restrict__ pos,
                                              const float* __restrict__ Wt,
                                              const float* __restrict__ Wpa,
                                              const float* __restrict__ b_attn,
                                              const float* __restrict__ Wda,
                                              float* __restrict__ t_attn,
                                              float* __restrict__ wd_sum,
                                              ushort* __restrict__ wdat) {
    __shared__ float At[64][68];
    __shared__ float Bt[64][64];
    int t = threadIdx.x;
    int bid = blockIdx.x;
    if (bid >= 192) {
        // wd_sum[k] = sum_o Wda[k][o]; wdat[o][k] = bf16(Wda[k][o])
        int k = bid - 192;
        float a0 = Wda[(size_t)k * 768 + t];
        float a1 = Wda[(size_t)k * 768 + 256 + t];
        float a2 = Wda[(size_t)k * 768 + 512 + t];
        wdat[(size_t)t * 64 + k]         = f2bf(a0);
        wdat[(size_t)(t + 256) * 64 + k] = f2bf(a1);
        wdat[(size_t)(t + 512) * 64 + k] = f2bf(a2);
        float s = a0 + a1 + a2;
#pragma unroll
        for (int off = 32; off; off >>= 1) s += __shfl_down(s, off, 64);
        if ((t & 63) == 0) At[0][t >> 6] = s;
        __syncthreads();
        if (t == 0) wd_sum[k] = At[0][0] + At[0][1] + At[0][2] + At[0][3];
        return;
    }
    int M0 = (bid & 15) * 64, N0 = (bid >> 4) * 64;
    int r0 = (t >> 4) * 4, o0 = (t & 15) * 4;
    float acc[16] = {};
    for (int kc = 0; kc < 13; ++kc) {
        __syncthreads();
        for (int f = t * 4; f < 4096; f += 1024) {
            int row = f >> 6, kcol = f & 63;
            float4 v;
            if (kc < 12) v = *(const float4*)&text[(size_t)(M0 + row) * 768 + kc * 64 + kcol];
            else         v = *(const float4*)&pos[(size_t)(M0 + row) * 64 + kcol];
            At[kcol + 0][row] = v.x; At[kcol + 1][row] = v.y;
            At[kcol + 2][row] = v.z; At[kcol + 3][row] = v.w;
        }
        for (int f = t * 4; f < 4096; f += 1024) {
            int kr = f >> 6, oc = f & 63;
            float4 v;
            if (kc < 12) v = *(const float4*)&Wt[(size_t)(kc * 64 + kr) * 768 + N0 + oc];
            else         v = *(const float4*)&Wpa[(size_t)kr * 768 + N0 + oc];
            *(float4*)&Bt[kr][oc] = v;
        }
        __syncthreads();
#pragma unroll 8
        for (int k = 0; k < 64; ++k) {
            float4 a = *(const float4*)&At[k][r0];
            float4 b = *(const float4*)&Bt[k][o0];
            float av[4] = {a.x, a.y, a.z, a.w};
            float bv[4] = {b.x, b.y, b.z, b.w};
#pragma unroll
            for (int i = 0; i < 4; ++i)
#pragma unroll
                for (int j = 0; j < 4; ++j) acc[i * 4 + j] += av[i] * bv[j];
        }
    }
    float4 bias = *(const float4*)&b_attn[N0 + o0];
    float bb[4] = {bias.x, bias.y, bias.z, bias.w};
#pragma unroll
    for (int i = 0; i < 4; ++i) {
        float4 o;
        o.x = acc[i * 4 + 0] + bb[0]; o.y = acc[i * 4 + 1] + bb[1];
        o.z = acc[i * 4 + 2] + bb[2]; o.w = acc[i * 4 + 3] + bb[3];
        *(float4*)&t_attn[(size_t)(M0 + r0 + i) * 768 + N0 + o0] = o;
    }
}

// ---------------- K2 (mega): scores -> softmax -> p, pd (fp32), r GEMM (bf16 MFMA, swapped operands) ----------------
// Round-2 probe: PLAIN float4 stores for r (drop nontemporal) -> let L2 write-combine the
// 64-B row segments into full 128-B lines before HBM eviction.
__global__ __launch_bounds__(256) void k_mega(const float* __restrict__ dep,
                                              const int* __restrict__ adj,
                                              const ushort* __restrict__ wdat,
                                              const float* __restrict__ t_attn,
                                              const float* __restrict__ wd_sum,
                                              float* __restrict__ r_out,
                                              float* __restrict__ out_p,
                                              float* __restrict__ pd_out) {
    __shared__ __align__(16) ushort db[128 * 72];  // dep tile bf16, [j][64k + 8 pad]
    __shared__ float wds[64];
    __shared__ float sc[128];
    __shared__ float pv[128];
    __shared__ float pdp[4][64];
    __shared__ float red[8];
    int t = threadIdx.x;
    int bi = blockIdx.x;
    const float* depb = dep + (size_t)bi * (128 * 64);
    // stage dep -> bf16 LDS (row-major [j][k], +8 pad)
#pragma unroll
    for (int it = 0; it < 8; ++it) {
        int f = t + it * 256;              // float4 index, 0..2047
        int j = f >> 4, k4 = f & 15;
        float4 v = *(const float4*)&depb[(size_t)f * 4];
        union { ushort u[4]; uint2 d; } pk;
        pk.u[0] = f2bf(v.x); pk.u[1] = f2bf(v.y);
        pk.u[2] = f2bf(v.z); pk.u[3] = f2bf(v.w);
        *(uint2*)&db[j * 72 + k4 * 4] = pk.d;
    }
    if (t < 64) wds[t] = wd_sum[t];
    const float* ta = t_attn + (size_t)bi * 768;
    // S_t = sum over o of t_attn row
    float s = ta[t] + ta[t + 256] + ta[t + 512];
#pragma unroll
    for (int off = 32; off; off >>= 1) s += __shfl_down(s, off, 64);
    if ((t & 63) == 0) red[t >> 6] = s;
    __syncthreads();
    float S_t = red[0] + red[1] + red[2] + red[3];
    // scores (fp32, dep from L2-hot global)
    if (t < 128) {
        const float* row = depb + (size_t)t * 64;
        float d = 0.f;
#pragma unroll
        for (int k4 = 0; k4 < 16; ++k4) {
            float4 v = *(const float4*)&row[k4 * 4];
            d += v.x * wds[k4 * 4 + 0] + v.y * wds[k4 * 4 + 1]
               + v.z * wds[k4 * 4 + 2] + v.w * wds[k4 * 4 + 3];
        }
        float sval = S_t + d;
        if (adj[(size_t)bi * 128 + t] == 0) sval += -1e30f;
        sc[t] = sval;
    }
    __syncthreads();
    if (t < 64) {
        float v = fmaxf(sc[t], sc[t + 64]);
#pragma unroll
        for (int off = 32; off; off >>= 1) v = fmaxf(v, __shfl_down(v, off, 64));
        if (t == 0) red[4] = v;
    }
    __syncthreads();
    if (t < 128) pv[t] = __expf(sc[t] - red[4]);
    __syncthreads();
    if (t < 64) {
        float v = pv[t] + pv[t + 64];
#pragma unroll
        for (int off = 32; off; off >>= 1) v += __shfl_down(v, off, 64);
        if (t == 0) red[5] = v;
    }
    __syncthreads();
    float inv = 1.0f / red[5];
    if (t < 128) {
        float pj = pv[t] * inv;
        pv[t] = pj;
        out_p[(size_t)bi * 128 + t] = pj;
    }
    __syncthreads();
    // pd[k] = sum_j p[j] * dep[j][k]  (fp32 from L2-hot global)
    {
        int kk = t & 63, seg = t >> 6;
        float a = 0.f;
#pragma unroll
        for (int jj = 0; jj < 32; ++jj)
            a += pv[seg * 32 + jj] * depb[(size_t)(seg * 32 + jj) * 64 + kk];
        pdp[seg][kk] = a;
    }
    __syncthreads();
    if (t < 64) pd_out[(size_t)bi * 64 + t] = pdp[0][t] + pdp[1][t] + pdp[2][t] + pdp[3][t];

    // ---- r GEMM via bf16 MFMA 16x16x32, swapped operands: D'[o][j], lane holds 4 consecutive o
    // of one row j -> float4 stores (PLAIN, L2 write-combining) ----
    int w = t >> 6, l = t & 63;
    int col = l & 15, q = l >> 4;
    short8 afr[2][2];
#pragma unroll
    for (int jt = 0; jt < 2; ++jt)
#pragma unroll
        for (int h = 0; h < 2; ++h)
            afr[jt][h] = *(const short8*)&db[(w * 32 + jt * 16 + col) * 72 + h * 32 + q * 8];
    float* rb = r_out + (size_t)bi * (128 * 768);
    for (int oc = 0; oc < 12; ++oc) {
        int O = oc * 64;
        short8 bfr[4][2];
#pragma unroll
        for (int ot = 0; ot < 4; ++ot)
#pragma unroll
            for (int h = 0; h < 2; ++h)
                bfr[ot][h] = *(const short8*)&wdat[(size_t)(O + ot * 16 + col) * 64 + h * 32 + q * 8];
        float4 tav[4];
#pragma unroll
        for (int ot = 0; ot < 4; ++ot) tav[ot] = *(const float4*)&ta[O + ot * 16 + q * 4];
#pragma unroll
        for (int ot = 0; ot < 4; ++ot) {
#pragma unroll
            for (int jt = 0; jt < 2; ++jt) {
                v4f acc = {0.f, 0.f, 0.f, 0.f};
                // D' = WdaT x dep^T : col = lane&15 = j_local, row = q*4+reg = o_local
                acc = __builtin_amdgcn_mfma_f32_16x16x32_bf16(bfr[ot][0], afr[jt][0], acc, 0, 0, 0);
                acc = __builtin_amdgcn_mfma_f32_16x16x32_bf16(bfr[ot][1], afr[jt][1], acc, 0, 0, 0);
                v4f o4;
                o4[0] = acc[0] + tav[ot].x;
                o4[1] = acc[1] + tav[ot].y;
                o4[2] = acc[2] + tav[ot].z;
                o4[3] = acc[3] + tav[ot].w;
                v4f* dst = (v4f*)(rb + (size_t)(w * 32 + jt * 16 + col) * 768 + O + ot * 16 + q * 4);
                *dst = o4;
            }
        }
    }
}

// ---------------- K3: output_sum = text + pos@Wp + bp + bd + pd@Wd (256 blocks x 4 rows) ----------------
__global__ __launch_bounds__(256) void k_out(const float* __restrict__ text,
                                             const float* __restrict__ pos,
                                             const float* __restrict__ Wp,
                                             const float* __restrict__ bp,
                                             const float* __restrict__ Wd,
                                             const float* __restrict__ bd,
                                             const float* __restrict__ pd,
                                             float* __restrict__ outp) {
    __shared__ float ps[4][64];
    __shared__ float pdl[4][64];
    int t = threadIdx.x;
    int bi0 = blockIdx.x * 4;
    {
        int g = t >> 6, k = t & 63;
        ps[g][k]  = pos[(size_t)(bi0 + g) * 64 + k];
        pdl[g][k] = pd[(size_t)(bi0 + g) * 64 + k];
    }
    __syncthreads();
    if (t < 192) {
        int d0 = t * 4;
        float acc[16] = {};
#pragma unroll 4
        for (int k = 0; k < 64; ++k) {
            float4 wp = *(const float4*)&Wp[(size_t)k * 768 + d0];
            float4 wd = *(const float4*)&Wd[(size_t)k * 768 + d0];
            float wpv[4] = {wp.x, wp.y, wp.z, wp.w};
            float wdv[4] = {wd.x, wd.y, wd.z, wd.w};
#pragma unroll
            for (int g = 0; g < 4; ++g) {
                float pk = ps[g][k], dk = pdl[g][k];
#pragma unroll
                for (int c = 0; c < 4; ++c) acc[g * 4 + c] += pk * wpv[c] + dk * wdv[c];
            }
        }
        float4 bpv = *(const float4*)&bp[d0];
        float4 bdv = *(const float4*)&bd[d0];
        float bb[4] = {bpv.x + bdv.x, bpv.y + bdv.y, bpv.z + bdv.z, bpv.w + bdv.w};
#pragma unroll
        for (int g = 0; g < 4; ++g) {
            float4 tx = *(const float4*)&text[(size_t)(bi0 + g) * 768 + d0];
            float4 o;
            o.x = acc[g * 4 + 0] + tx.x + bb[0];
            o.y = acc[g * 4 + 1] + tx.y + bb[1];
            o.z = acc[g * 4 + 2] + tx.z + bb[2];
            o.w = acc[g * 4 + 3] + tx.w + bb[3];
            *(float4*)&outp[(size_t)(bi0 + g) * 768 + d0] = o;
        }
    }
}

extern "C" void kernel_launch(void* const* d_in, const int* in_sizes, int n_in,
                              void* d_out, int out_size, void* d_ws, size_t ws_size,
                              hipStream_t stream) {
    const float* text   = (const float*)d_in[0];
    const int*   adj    = (const int*)d_in[1];
    const float* dep    = (const float*)d_in[2];
    const float* pos    = (const float*)d_in[3];
    const float* Wt     = (const float*)d_in[4];
    const float* Wpa    = (const float*)d_in[5];
    const float* Wda    = (const float*)d_in[6];
    const float* b_attn = (const float*)d_in[7];
    const float* Wd     = (const float*)d_in[8];
    const float* bd     = (const float*)d_in[9];
    const float* Wp     = (const float*)d_in[10];
    const float* bp     = (const float*)d_in[11];

    float* out    = (float*)d_out;
    float* r_out  = out;                                   // [8,128,128,768]
    float* os_out = out + (size_t)8 * 128 * 128 * 768;     // [8,128,768]
    float* p_out  = os_out + (size_t)8 * 128 * 768;        // [8,128,128]

    float* ws     = (float*)d_ws;
    float* t_attn = ws;                    // 786432 floats
    float* wd_sum = ws + 786432;           // 64
    float* pd     = ws + 786496;           // 65536
    ushort* wdat  = (ushort*)(ws + 852032);  // 49152 ushorts, 16B-aligned

    k_prep<<<256, 256, 0, stream>>>(text, pos, Wt, Wpa, b_attn, Wda, t_attn, wd_sum, wdat);
    k_mega<<<1024, 256, 0, stream>>>(dep, adj, wdat, t_attn, wd_sum, r_out, p_out, pd);
    k_out<<<256, 256, 0, stream>>>(text, pos, Wp, bp, Wd, bd, pd, os_out);
}

// Round 3
// 571.057 us; speedup vs baseline: 1.0876x; 1.0373x over previous
//
#include <hip/hip_runtime.h>
#include <hip/hip_bf16.h>

typedef float v4f __attribute__((ext_vector_type(4)));
typedef short short8 __attribute__((ext_vector_type(8)));

__device__ inline ushort f2bf(float x) {
    unsigned u = __float_as_uint(x);
    unsigned r = u + 0x7fffu + ((u >> 16) & 1u);
    return (ushort)(r >> 16);
}

// ---------------- K0: wd_sum[k] = sum_o Wda[k][o]; wdat[o][k] = bf16(Wda[k][o]) ----------------
__global__ __launch_bounds__(256) void k_cvt64(const float* __restrict__ Wda,
                                               float* __restrict__ wd_sum,
                                               ushort* __restrict__ wdat) {
    __shared__ float red4[4];
    int k = blockIdx.x, t = threadIdx.x;
    float a0 = Wda[(size_t)k * 768 + t];
    float a1 = Wda[(size_t)k * 768 + 256 + t];
    float a2 = Wda[(size_t)k * 768 + 512 + t];
    wdat[(size_t)t * 64 + k]         = f2bf(a0);
    wdat[(size_t)(t + 256) * 64 + k] = f2bf(a1);
    wdat[(size_t)(t + 512) * 64 + k] = f2bf(a2);
    float s = a0 + a1 + a2;
#pragma unroll
    for (int off = 32; off; off >>= 1) s += __shfl_down(s, off, 64);
    if ((t & 63) == 0) red4[t >> 6] = s;
    __syncthreads();
    if (t == 0) wd_sum[k] = red4[0] + red4[1] + red4[2] + red4[3];
}

// ---------------- K1: t_attn partials, K-split x2 for occupancy ----------------
// kh=0: kc 0..6 (+bias) -> tA ; kh=1: kc 7..12 -> tB. 384 blocks (~2/CU) instead of 192 (1/CU).
__global__ __launch_bounds__(256) void k_tattn(const float* __restrict__ text,
                                               const float* __restrict__ pos,
                                               const float* __restrict__ Wt,
                                               const float* __restrict__ Wpa,
                                               const float* __restrict__ b_attn,
                                               float* __restrict__ tA,
                                               float* __restrict__ tB) {
    __shared__ float At[64][68];
    __shared__ float Bt[64][64];
    int t = threadIdx.x;
    int M0 = blockIdx.x * 64, N0 = blockIdx.y * 64;
    int kh = blockIdx.z;
    int kc0 = kh ? 7 : 0, kc1 = kh ? 13 : 7;
    int r0 = (t >> 4) * 4, o0 = (t & 15) * 4;
    float acc[16] = {};
    for (int kc = kc0; kc < kc1; ++kc) {
        __syncthreads();
        for (int f = t * 4; f < 4096; f += 1024) {
            int row = f >> 6, kcol = f & 63;
            float4 v;
            if (kc < 12) v = *(const float4*)&text[(size_t)(M0 + row) * 768 + kc * 64 + kcol];
            else         v = *(const float4*)&pos[(size_t)(M0 + row) * 64 + kcol];
            At[kcol + 0][row] = v.x; At[kcol + 1][row] = v.y;
            At[kcol + 2][row] = v.z; At[kcol + 3][row] = v.w;
        }
        for (int f = t * 4; f < 4096; f += 1024) {
            int kr = f >> 6, oc = f & 63;
            float4 v;
            if (kc < 12) v = *(const float4*)&Wt[(size_t)(kc * 64 + kr) * 768 + N0 + oc];
            else         v = *(const float4*)&Wpa[(size_t)kr * 768 + N0 + oc];
            *(float4*)&Bt[kr][oc] = v;
        }
        __syncthreads();
#pragma unroll 8
        for (int k = 0; k < 64; ++k) {
            float4 a = *(const float4*)&At[k][r0];
            float4 b = *(const float4*)&Bt[k][o0];
            float av[4] = {a.x, a.y, a.z, a.w};
            float bv[4] = {b.x, b.y, b.z, b.w};
#pragma unroll
            for (int i = 0; i < 4; ++i)
#pragma unroll
                for (int j = 0; j < 4; ++j) acc[i * 4 + j] += av[i] * bv[j];
        }
    }
    float* dst = kh ? tB : tA;
    float bb[4] = {0.f, 0.f, 0.f, 0.f};
    if (kh == 0) {
        float4 bias = *(const float4*)&b_attn[N0 + o0];
        bb[0] = bias.x; bb[1] = bias.y; bb[2] = bias.z; bb[3] = bias.w;
    }
#pragma unroll
    for (int i = 0; i < 4; ++i) {
        float4 o;
        o.x = acc[i * 4 + 0] + bb[0]; o.y = acc[i * 4 + 1] + bb[1];
        o.z = acc[i * 4 + 2] + bb[2]; o.w = acc[i * 4 + 3] + bb[3];
        *(float4*)&dst[(size_t)(M0 + r0 + i) * 768 + N0 + o0] = o;
    }
}

// ---------------- K2 (mega): scores -> softmax -> p, pd (fp32), r GEMM (bf16 MFMA) ----------------
// ta row = tA + tB summed ONCE into LDS at prologue; epilogue reads LDS (broadcast, conflict-free).
__global__ __launch_bounds__(256) void k_mega(const float* __restrict__ dep,
                                              const int* __restrict__ adj,
                                              const ushort* __restrict__ wdat,
                                              const float* __restrict__ tA,
                                              const float* __restrict__ tB,
                                              const float* __restrict__ wd_sum,
                                              float* __restrict__ r_out,
                                              float* __restrict__ out_p,
                                              float* __restrict__ pd_out) {
    __shared__ __align__(16) ushort db[128 * 72];  // dep tile bf16, [j][64k + 8 pad]
    __shared__ float tsl[768];
    __shared__ float wds[64];
    __shared__ float sc[128];
    __shared__ float pv[128];
    __shared__ float pdp[4][64];
    __shared__ float red[8];
    int t = threadIdx.x;
    int bi = blockIdx.x;
    const float* depb = dep + (size_t)bi * (128 * 64);
    // stage dep -> bf16 LDS (row-major [j][k], +8 pad)
#pragma unroll
    for (int it = 0; it < 8; ++it) {
        int f = t + it * 256;              // float4 index, 0..2047
        int j = f >> 4, k4 = f & 15;
        float4 v = *(const float4*)&depb[(size_t)f * 4];
        union { ushort u[4]; uint2 d; } pk;
        pk.u[0] = f2bf(v.x); pk.u[1] = f2bf(v.y);
        pk.u[2] = f2bf(v.z); pk.u[3] = f2bf(v.w);
        *(uint2*)&db[j * 72 + k4 * 4] = pk.d;
    }
    if (t < 64) wds[t] = wd_sum[t];
    const float* taA = tA + (size_t)bi * 768;
    const float* taB = tB + (size_t)bi * 768;
    // ta = tA + tB into LDS; S_t = sum over o
    float v0 = taA[t]       + taB[t];
    float v1 = taA[t + 256] + taB[t + 256];
    float v2 = taA[t + 512] + taB[t + 512];
    tsl[t] = v0; tsl[t + 256] = v1; tsl[t + 512] = v2;
    float s = v0 + v1 + v2;
#pragma unroll
    for (int off = 32; off; off >>= 1) s += __shfl_down(s, off, 64);
    if ((t & 63) == 0) red[t >> 6] = s;
    __syncthreads();
    float S_t = red[0] + red[1] + red[2] + red[3];
    // scores (fp32, dep from L2-hot global)
    if (t < 128) {
        const float* row = depb + (size_t)t * 64;
        float d = 0.f;
#pragma unroll
        for (int k4 = 0; k4 < 16; ++k4) {
            float4 v = *(const float4*)&row[k4 * 4];
            d += v.x * wds[k4 * 4 + 0] + v.y * wds[k4 * 4 + 1]
               + v.z * wds[k4 * 4 + 2] + v.w * wds[k4 * 4 + 3];
        }
        float sval = S_t + d;
        if (adj[(size_t)bi * 128 + t] == 0) sval += -1e30f;
        sc[t] = sval;
    }
    __syncthreads();
    if (t < 64) {
        float v = fmaxf(sc[t], sc[t + 64]);
#pragma unroll
        for (int off = 32; off; off >>= 1) v = fmaxf(v, __shfl_down(v, off, 64));
        if (t == 0) red[4] = v;
    }
    __syncthreads();
    if (t < 128) pv[t] = __expf(sc[t] - red[4]);
    __syncthreads();
    if (t < 64) {
        float v = pv[t] + pv[t + 64];
#pragma unroll
        for (int off = 32; off; off >>= 1) v += __shfl_down(v, off, 64);
        if (t == 0) red[5] = v;
    }
    __syncthreads();
    float inv = 1.0f / red[5];
    if (t < 128) {
        float pj = pv[t] * inv;
        pv[t] = pj;
        out_p[(size_t)bi * 128 + t] = pj;
    }
    __syncthreads();
    // pd[k] = sum_j p[j] * dep[j][k]  (fp32 from L2-hot global)
    {
        int kk = t & 63, seg = t >> 6;
        float a = 0.f;
#pragma unroll
        for (int jj = 0; jj < 32; ++jj)
            a += pv[seg * 32 + jj] * depb[(size_t)(seg * 32 + jj) * 64 + kk];
        pdp[seg][kk] = a;
    }
    __syncthreads();
    if (t < 64) pd_out[(size_t)bi * 64 + t] = pdp[0][t] + pdp[1][t] + pdp[2][t] + pdp[3][t];

    // ---- r GEMM via bf16 MFMA 16x16x32, swapped operands: D'[o][j], lane holds 4 consecutive o
    // of one row j -> plain float4 stores (L2 write-combining) ----
    int w = t >> 6, l = t & 63;
    int col = l & 15, q = l >> 4;
    short8 afr[2][2];
#pragma unroll
    for (int jt = 0; jt < 2; ++jt)
#pragma unroll
        for (int h = 0; h < 2; ++h)
            afr[jt][h] = *(const short8*)&db[(w * 32 + jt * 16 + col) * 72 + h * 32 + q * 8];
    float* rb = r_out + (size_t)bi * (128 * 768);
    for (int oc = 0; oc < 12; ++oc) {
        int O = oc * 64;
        short8 bfr[4][2];
#pragma unroll
        for (int ot = 0; ot < 4; ++ot)
#pragma unroll
            for (int h = 0; h < 2; ++h)
                bfr[ot][h] = *(const short8*)&wdat[(size_t)(O + ot * 16 + col) * 64 + h * 32 + q * 8];
        float4 tav[4];
#pragma unroll
        for (int ot = 0; ot < 4; ++ot) tav[ot] = *(const float4*)&tsl[O + ot * 16 + q * 4];
#pragma unroll
        for (int ot = 0; ot < 4; ++ot) {
#pragma unroll
            for (int jt = 0; jt < 2; ++jt) {
                v4f acc = {0.f, 0.f, 0.f, 0.f};
                // D' = WdaT x dep^T : col = lane&15 = j_local, row = q*4+reg = o_local
                acc = __builtin_amdgcn_mfma_f32_16x16x32_bf16(bfr[ot][0], afr[jt][0], acc, 0, 0, 0);
                acc = __builtin_amdgcn_mfma_f32_16x16x32_bf16(bfr[ot][1], afr[jt][1], acc, 0, 0, 0);
                v4f o4;
                o4[0] = acc[0] + tav[ot].x;
                o4[1] = acc[1] + tav[ot].y;
                o4[2] = acc[2] + tav[ot].z;
                o4[3] = acc[3] + tav[ot].w;
                v4f* dst = (v4f*)(rb + (size_t)(w * 32 + jt * 16 + col) * 768 + O + ot * 16 + q * 4);
                *dst = o4;
            }
        }
    }
}

// ---------------- K3: output_sum = text + pos@Wp + bp + bd + pd@Wd (256 blocks x 4 rows) ----------------
__global__ __launch_bounds__(256) void k_out(const float* __restrict__ text,
                                             const float* __restrict__ pos,
                                             const float* __restrict__ Wp,
                                             const float* __restrict__ bp,
                                             const float* __restrict__ Wd,
                                             const float* __restrict__ bd,
                                             const float* __restrict__ pd,
                                             float* __restrict__ outp) {
    __shared__ float ps[4][64];
    __shared__ float pdl[4][64];
    int t = threadIdx.x;
    int bi0 = blockIdx.x * 4;
    {
        int g = t >> 6, k = t & 63;
        ps[g][k]  = pos[(size_t)(bi0 + g) * 64 + k];
        pdl[g][k] = pd[(size_t)(bi0 + g) * 64 + k];
    }
    __syncthreads();
    if (t < 192) {
        int d0 = t * 4;
        float acc[16] = {};
#pragma unroll 4
        for (int k = 0; k < 64; ++k) {
            float4 wp = *(const float4*)&Wp[(size_t)k * 768 + d0];
            float4 wd = *(const float4*)&Wd[(size_t)k * 768 + d0];
            float wpv[4] = {wp.x, wp.y, wp.z, wp.w};
            float wdv[4] = {wd.x, wd.y, wd.z, wd.w};
#pragma unroll
            for (int g = 0; g < 4; ++g) {
                float pk = ps[g][k], dk = pdl[g][k];
#pragma unroll
                for (int c = 0; c < 4; ++c) acc[g * 4 + c] += pk * wpv[c] + dk * wdv[c];
            }
        }
        float4 bpv = *(const float4*)&bp[d0];
        float4 bdv = *(const float4*)&bd[d0];
        float bb[4] = {bpv.x + bdv.x, bpv.y + bdv.y, bpv.z + bdv.z, bpv.w + bdv.w};
#pragma unroll
        for (int g = 0; g < 4; ++g) {
            float4 tx = *(const float4*)&text[(size_t)(bi0 + g) * 768 + d0];
            float4 o;
            o.x = acc[g * 4 + 0] + tx.x + bb[0];
            o.y = acc[g * 4 + 1] + tx.y + bb[1];
            o.z = acc[g * 4 + 2] + tx.z + bb[2];
            o.w = acc[g * 4 + 3] + tx.w + bb[3];
            *(float4*)&outp[(size_t)(bi0 + g) * 768 + d0] = o;
        }
    }
}

extern "C" void kernel_launch(void* const* d_in, const int* in_sizes, int n_in,
                              void* d_out, int out_size, void* d_ws, size_t ws_size,
                              hipStream_t stream) {
    const float* text   = (const float*)d_in[0];
    const int*   adj    = (const int*)d_in[1];
    const float* dep    = (const float*)d_in[2];
    const float* pos    = (const float*)d_in[3];
    const float* Wt     = (const float*)d_in[4];
    const float* Wpa    = (const float*)d_in[5];
    const float* Wda    = (const float*)d_in[6];
    const float* b_attn = (const float*)d_in[7];
    const float* Wd     = (const float*)d_in[8];
    const float* bd     = (const float*)d_in[9];
    const float* Wp     = (const float*)d_in[10];
    const float* bp     = (const float*)d_in[11];

    float* out    = (float*)d_out;
    float* r_out  = out;                                   // [8,128,128,768]
    float* os_out = out + (size_t)8 * 128 * 128 * 768;     // [8,128,768]
    float* p_out  = os_out + (size_t)8 * 128 * 768;        // [8,128,128]

    float* ws     = (float*)d_ws;
    float* tA     = ws;                      // 786432 floats
    float* tB     = ws + 786432;             // 786432 floats
    float* wd_sum = ws + 1572864;            // 64
    float* pd     = ws + 1572928;            // 65536
    ushort* wdat  = (ushort*)(ws + 1638464); // 49152 ushorts, 16B-aligned

    k_cvt64<<<64, 256, 0, stream>>>(Wda, wd_sum, wdat);
    k_tattn<<<dim3(16, 12, 2), 256, 0, stream>>>(text, pos, Wt, Wpa, b_attn, tA, tB);
    k_mega<<<1024, 256, 0, stream>>>(dep, adj, wdat, tA, tB, wd_sum, r_out, p_out, pd);
    k_out<<<256, 256, 0, stream>>>(text, pos, Wp, bp, Wd, bd, pd, os_out);
}